// Round 9
// baseline (477.815 us; speedup 1.0000x reference)
//
#include <hip/hip_runtime.h>
#include <stdint.h>

typedef unsigned short u16;
typedef __attribute__((ext_vector_type(8))) short short8;
typedef __attribute__((ext_vector_type(4))) float f32x4;

#define BB 4
#define TT 1024
#define CC 1024
#define HH 16
#define NN 64
#define MM (BB*TT)        // 4096 rows
#define FFN_ 4096
#define PCH 16            // WKV chunks
#define LCH (TT/PCH)      // 64 steps per chunk
static constexpr float EPS_ = 1e-5f;

__device__ __forceinline__ u16 f2bf(float f) {
    union { float f; uint32_t u; } x; x.f = f;
    uint32_t r = x.u + 0x7fff + ((x.u >> 16) & 1);   // RNE
    return (u16)(r >> 16);
}
__device__ __forceinline__ float bf2f(u16 b) {
    union { uint32_t u; float f; } x; x.u = ((uint32_t)b) << 16; return x.f;
}

#define VMW8() asm volatile("s_waitcnt vmcnt(8)" ::: "memory")
#define VMW4() asm volatile("s_waitcnt vmcnt(4)" ::: "memory")
#define VMW0() asm volatile("s_waitcnt vmcnt(0)" ::: "memory")
#define BARRIER() do { asm volatile("" ::: "memory"); __builtin_amdgcn_s_barrier(); asm volatile("" ::: "memory"); } while (0)

// ---------------- LayerNorm -> concat-bf16 z (LN1 only) ----------------
__global__ __launch_bounds__(256) void lnz_kernel(const float* __restrict__ x,
    const float* __restrict__ w, const float* __restrict__ b, u16* __restrict__ z)
{
    int row = blockIdx.x;
    int tid = threadIdx.x;
    const float* xr = x + (size_t)row * CC;
    float4 v = ((const float4*)xr)[tid];
    float s  = v.x + v.y + v.z + v.w;
    float ss = v.x*v.x + v.y*v.y + v.z*v.z + v.w*v.w;
#pragma unroll
    for (int m = 1; m < 64; m <<= 1) { s += __shfl_xor(s, m); ss += __shfl_xor(ss, m); }
    __shared__ float as_[4], bs_[4];
    int wv = tid >> 6, ln = tid & 63;
    if (ln == 0) { as_[wv] = s; bs_[wv] = ss; }
    __syncthreads();
    s  = as_[0] + as_[1] + as_[2] + as_[3];
    ss = bs_[0] + bs_[1] + bs_[2] + bs_[3];
    float mean = s * (1.f / CC);
    float var  = ss * (1.f / CC) - mean * mean;
    float inv  = rsqrtf(var + EPS_);
    float4 w4 = ((const float4*)w)[tid];
    float4 b4 = ((const float4*)b)[tid];
    ushort4 o;
    o.x = f2bf((v.x - mean) * inv * w4.x + b4.x);
    o.y = f2bf((v.y - mean) * inv * w4.y + b4.y);
    o.z = f2bf((v.z - mean) * inv * w4.z + b4.z);
    o.w = f2bf((v.w - mean) * inv * w4.w + b4.w);
    int t = row & (TT - 1);
    *(ushort4*)(z + (size_t)row * 2048 + tid * 4) = o;
    if (t < TT - 1) *(ushort4*)(z + (size_t)(row + 1) * 2048 + 1024 + tid * 4) = o;
    if (t == 0) {
        ushort4 zz; zz.x = 0; zz.y = 0; zz.z = 0; zz.w = 0;
        *(ushort4*)(z + (size_t)row * 2048 + 1024 + tid * 4) = zz;
    }
}

// ---------------- fused LN2 + channel-mix: x1 -> xk, xr (bf16) ----------------
__global__ __launch_bounds__(256) void ln2m_kernel(const float* __restrict__ x1,
    const float* __restrict__ w, const float* __restrict__ b,
    const float* __restrict__ mk, const float* __restrict__ mr,
    u16* __restrict__ xk, u16* __restrict__ xr)
{
    int row = blockIdx.x;
    int tid = threadIdx.x;
    int t = row & (TT - 1);
    float4 vc = ((const float4*)(x1 + (size_t)row * CC))[tid];
    float4 vp = make_float4(0.f, 0.f, 0.f, 0.f);
    if (t) vp = ((const float4*)(x1 + (size_t)(row - 1) * CC))[tid];
    float sc  = vc.x + vc.y + vc.z + vc.w;
    float ssc = vc.x*vc.x + vc.y*vc.y + vc.z*vc.z + vc.w*vc.w;
    float sp  = vp.x + vp.y + vp.z + vp.w;
    float ssp = vp.x*vp.x + vp.y*vp.y + vp.z*vp.z + vp.w*vp.w;
#pragma unroll
    for (int m = 1; m < 64; m <<= 1) {
        sc += __shfl_xor(sc, m); ssc += __shfl_xor(ssc, m);
        sp += __shfl_xor(sp, m); ssp += __shfl_xor(ssp, m);
    }
    __shared__ float red[4][4];
    int wv = tid >> 6, ln = tid & 63;
    if (ln == 0) { red[wv][0] = sc; red[wv][1] = ssc; red[wv][2] = sp; red[wv][3] = ssp; }
    __syncthreads();
    sc  = red[0][0] + red[1][0] + red[2][0] + red[3][0];
    ssc = red[0][1] + red[1][1] + red[2][1] + red[3][1];
    sp  = red[0][2] + red[1][2] + red[2][2] + red[3][2];
    ssp = red[0][3] + red[1][3] + red[2][3] + red[3][3];
    float mc = sc * (1.f / CC);
    float invc = rsqrtf(ssc * (1.f / CC) - mc * mc + EPS_);
    float mp = sp * (1.f / CC);
    float invp = rsqrtf(ssp * (1.f / CC) - mp * mp + EPS_);
    float4 w4 = ((const float4*)w)[tid];
    float4 b4 = ((const float4*)b)[tid];
    int c = tid << 2;
    float4 k4 = *(const float4*)(mk + c);
    float4 r4 = *(const float4*)(mr + c);
    float lc0 = (vc.x - mc) * invc * w4.x + b4.x;
    float lc1 = (vc.y - mc) * invc * w4.y + b4.y;
    float lc2 = (vc.z - mc) * invc * w4.z + b4.z;
    float lc3 = (vc.w - mc) * invc * w4.w + b4.w;
    float lp0 = t ? (vp.x - mp) * invp * w4.x + b4.x : 0.f;
    float lp1 = t ? (vp.y - mp) * invp * w4.y + b4.y : 0.f;
    float lp2 = t ? (vp.z - mp) * invp * w4.z + b4.z : 0.f;
    float lp3 = t ? (vp.w - mp) * invp * w4.w + b4.w : 0.f;
    ushort4 ok, orr;
    ok.x  = f2bf(lp0 + k4.x * (lc0 - lp0)); ok.y  = f2bf(lp1 + k4.y * (lc1 - lp1));
    ok.z  = f2bf(lp2 + k4.z * (lc2 - lp2)); ok.w  = f2bf(lp3 + k4.w * (lc3 - lp3));
    orr.x = f2bf(lp0 + r4.x * (lc0 - lp0)); orr.y = f2bf(lp1 + r4.y * (lc1 - lp1));
    orr.z = f2bf(lp2 + r4.z * (lc2 - lp2)); orr.w = f2bf(lp3 + r4.w * (lc3 - lp3));
    size_t f = (size_t)row * 1024 + c;
    *(ushort4*)(xk + f) = ok;
    *(ushort4*)(xr + f) = orr;
}

// ---------------- merged weight prep: W4 build + 4 bf16 conversions, ONE launch ----------------
struct PrepArgs {
    const float *Wr, *Wk, *Wv, *Wg, *mr, *mk, *mv, *mg;
    u16* W4p;
    const float* csrc[4];
    u16* cdst[4];
    int cstart4[4];    // {0, q, 5q, 6q}
    int ctotal4;       // 10q
};
__global__ __launch_bounds__(256) void prep_kernel(PrepArgs a)
{
    int bid = blockIdx.x;
    if (bid < 4096) {
        int idx = bid * 256 + threadIdx.x;
        int n = idx >> 8, c = (idx & 255) << 2;
        int sel = n >> 10, nr = n & 1023;
        const float* W = sel == 0 ? a.Wr : sel == 1 ? a.Wk : sel == 2 ? a.Wv : a.Wg;
        const float* mx = sel == 0 ? a.mr : sel == 1 ? a.mk : sel == 2 ? a.mv : a.mg;
        float4 w4 = *(const float4*)(W + (size_t)nr * 1024 + c);
        float4 m4 = *(const float4*)(mx + c);
        ushort4 p, q4;
        p.x  = f2bf(w4.x * m4.x); p.y  = f2bf(w4.y * m4.y);
        p.z  = f2bf(w4.z * m4.z); p.w  = f2bf(w4.w * m4.w);
        q4.x = f2bf(w4.x * (1.f - m4.x)); q4.y = f2bf(w4.y * (1.f - m4.y));
        q4.z = f2bf(w4.z * (1.f - m4.z)); q4.w = f2bf(w4.w * (1.f - m4.w));
        *(ushort4*)(a.W4p + (size_t)n * 2048 + c) = p;
        *(ushort4*)(a.W4p + (size_t)n * 2048 + 1024 + c) = q4;
    } else {
        int i4 = (bid - 4096) * 256 + threadIdx.x;
        if (i4 >= a.ctotal4) return;
        int s = 0;
#pragma unroll
        for (int j = 1; j < 4; ++j) if (i4 >= a.cstart4[j]) s = j;
        int l4 = i4 - a.cstart4[s];
        float4 v = ((const float4*)a.csrc[s])[l4];
        ushort4 o; o.x = f2bf(v.x); o.y = f2bf(v.y); o.z = f2bf(v.z); o.w = f2bf(v.w);
        ((ushort4*)a.cdst[s])[l4] = o;
    }
}

// ================ 256x256-tile ring-4 bf16 GEMM (r3-proven schedule) ================
__device__ __forceinline__ void stage_tile(const u16* gbase, int rbase, int ldk,
                                           int kcol, u16* ldsbase, int tid)
{
#pragma unroll
    for (int rd = 0; rd < 2; ++rd) {
        int row = rd * 128 + (tid >> 2);
        int slog = (tid & 3) ^ ((row >> 1) & 3);           // T2 pre-swizzled source
        const u16* src = gbase + (size_t)(rbase + row) * ldk + kcol + (slog << 3);
        u16* dst = ldsbase + row * 32 + ((tid & 3) << 3);  // linear dest
        __builtin_amdgcn_global_load_lds(
            (const __attribute__((address_space(1))) uint32_t*)(const void*)src,
            (__attribute__((address_space(3))) uint32_t*)(void*)dst, 16, 0, 0);
    }
}

// EPI: 3 relu(v)^2 -> bf16 | 6 rkvg (silu for cols>=3072) | 7 split-K partial f32
template<int EPI>
__global__ __launch_bounds__(512, 2) void gemm8(
    const u16* __restrict__ A, const u16* __restrict__ Bw,
    float* __restrict__ Cf, u16* __restrict__ Cbf,
    int Mdim, int Ndim, int Kdim, int kLen)
{
    __shared__ u16 As[4 * 8192];
    __shared__ u16 Bs[4 * 8192];
    int tid = threadIdx.x;
    int wid = tid >> 6, lane = tid & 63;
    int wm = wid >> 2, wn = wid & 3;
    int f = lane & 15, g = lane >> 4;

    int nwg = gridDim.x * gridDim.y;
    int bid = blockIdx.y * gridDim.x + blockIdx.x;
    int qq = nwg >> 3, r8 = nwg & 7;
    int xcd = bid & 7, lid = bid >> 3;
    int swz = (xcd < r8 ? xcd * (qq + 1) : r8 * (qq + 1) + (xcd - r8) * qq) + lid;
    int bx = swz % gridDim.x, by = swz / gridDim.x;
    int rowBase = by * 256, colBase = bx * 256;
    int kOff = blockIdx.z * kLen;
    int NT = kLen >> 5;
    if (EPI == 7) Cf += (size_t)blockIdx.z * Mdim * Ndim;

    f32x4 acc[8][4] = {};

    stage_tile(A,  rowBase, Kdim, kOff,      As, tid);
    stage_tile(Bw, colBase, Kdim, kOff,      Bs, tid);
    if (NT > 1) {
        stage_tile(A,  rowBase, Kdim, kOff + 32, As + 8192, tid);
        stage_tile(Bw, colBase, Kdim, kOff + 32, Bs + 8192, tid);
    }
    if (NT > 2) {
        stage_tile(A,  rowBase, Kdim, kOff + 64, As + 2 * 8192, tid);
        stage_tile(Bw, colBase, Kdim, kOff + 64, Bs + 2 * 8192, tid);
    }

    for (int t = 0; t < NT; ++t) {
        if (t < NT - 2) { VMW8(); } else if (t == NT - 2) { VMW4(); } else { VMW0(); }
        BARRIER();
        const u16* Asl = As + (t & 3) * 8192;
        const u16* Bsl = Bs + (t & 3) * 8192;
        short8 bfr[4], afr[4];
#pragma unroll
        for (int n = 0; n < 4; ++n) {
            int row = wn * 64 + n * 16 + f;
            bfr[n] = *(const short8*)(Bsl + row * 32 + ((g ^ ((row >> 1) & 3)) << 3));
        }
#pragma unroll
        for (int m = 0; m < 4; ++m) {
            int row = wm * 128 + m * 16 + f;
            afr[m] = *(const short8*)(Asl + row * 32 + ((g ^ ((row >> 1) & 3)) << 3));
        }
        if (t + 3 < NT)
            stage_tile(A, rowBase, Kdim, kOff + (t + 3) * 32, As + ((t + 3) & 3) * 8192, tid);
        __builtin_amdgcn_s_setprio(1);
#pragma unroll
        for (int m = 0; m < 4; ++m)
#pragma unroll
            for (int n = 0; n < 4; ++n)
                acc[m][n] = __builtin_amdgcn_mfma_f32_16x16x32_bf16(afr[m], bfr[n], acc[m][n], 0, 0, 0);
        __builtin_amdgcn_s_setprio(0);
#pragma unroll
        for (int m = 0; m < 4; ++m) {
            int row = wm * 128 + 64 + m * 16 + f;
            afr[m] = *(const short8*)(Asl + row * 32 + ((g ^ ((row >> 1) & 3)) << 3));
        }
        if (t + 3 < NT)
            stage_tile(Bw, colBase, Kdim, kOff + (t + 3) * 32, Bs + ((t + 3) & 3) * 8192, tid);
        __builtin_amdgcn_s_setprio(1);
#pragma unroll
        for (int m = 0; m < 4; ++m)
#pragma unroll
            for (int n = 0; n < 4; ++n)
                acc[4 + m][n] = __builtin_amdgcn_mfma_f32_16x16x32_bf16(afr[m], bfr[n], acc[4 + m][n], 0, 0, 0);
        __builtin_amdgcn_s_setprio(0);
    }

    int r0 = rowBase + wm * 128, c0 = colBase + wn * 64;
    bool dsilu = (EPI == 6) && (colBase >= 3072);
#pragma unroll
    for (int am = 0; am < 8; ++am) {
#pragma unroll
        for (int n = 0; n < 4; ++n) {
#pragma unroll
            for (int rg = 0; rg < 4; ++rg) {
                int gr = r0 + am * 16 + (lane >> 4) * 4 + rg;
                int gc = c0 + n * 16 + (lane & 15);
                size_t idx = (size_t)gr * Ndim + gc;
                float v = acc[am][n][rg];
                if (EPI == 3) { float rr = v > 0.f ? v : 0.f; Cbf[idx] = f2bf(rr * rr); }
                else if (EPI == 6) Cf[idx] = dsilu ? v / (1.f + __expf(-v)) : v;
                else Cf[idx] = v;
            }
        }
    }
}

// ================ 128x128-tile ring-4 bf16 GEMM for N=1024 shapes ================
__device__ __forceinline__ void stage_tile128(const u16* gbase, int rbase, int ldk,
                                              int kcol, u16* ldsbase, int tid)
{
#pragma unroll
    for (int rd = 0; rd < 2; ++rd) {
        int row = rd * 64 + (tid >> 2);
        int slog = (tid & 3) ^ ((row >> 1) & 3);
        const u16* src = gbase + (size_t)(rbase + row) * ldk + kcol + (slog << 3);
        u16* dst = ldsbase + row * 32 + ((tid & 3) << 3);
        __builtin_amdgcn_global_load_lds(
            (const __attribute__((address_space(1))) uint32_t*)(const void*)src,
            (__attribute__((address_space(3))) uint32_t*)(void*)dst, 16, 0, 0);
    }
}

// EPI: 2 aux1+v f32 | 4 sigmoid f32
template<int EPI>
__global__ __launch_bounds__(256, 2) void gemmr(
    const u16* __restrict__ A, const u16* __restrict__ Bw,
    float* __restrict__ Cf,
    const float* __restrict__ aux1,
    int Mdim, int Ndim, int Kdim)
{
    __shared__ u16 As[4 * 4096];   // 32 KiB
    __shared__ u16 Bs[4 * 4096];   // 32 KiB
    int tid = threadIdx.x;
    int wid = tid >> 6, lane = tid & 63;
    int wm = wid >> 1, wn = wid & 1;
    int f = lane & 15, g = lane >> 4;

    int nwg = gridDim.x * gridDim.y;
    int bid = blockIdx.y * gridDim.x + blockIdx.x;
    int qq = nwg >> 3, r8 = nwg & 7;
    int xcd = bid & 7, lid = bid >> 3;
    int swz = (xcd < r8 ? xcd * (qq + 1) : r8 * (qq + 1) + (xcd - r8) * qq) + lid;
    int bx = swz % gridDim.x, by = swz / gridDim.x;
    int rowBase = by * 128, colBase = bx * 128;
    int NT = Kdim >> 5;

    f32x4 acc[4][4] = {};

    stage_tile128(A,  rowBase, Kdim, 0,  As, tid);
    stage_tile128(Bw, colBase, Kdim, 0,  Bs, tid);
    stage_tile128(A,  rowBase, Kdim, 32, As + 4096, tid);
    stage_tile128(Bw, colBase, Kdim, 32, Bs + 4096, tid);
    stage_tile128(A,  rowBase, Kdim, 64, As + 2 * 4096, tid);
    stage_tile128(Bw, colBase, Kdim, 64, Bs + 2 * 4096, tid);

    for (int t = 0; t < NT; ++t) {
        if (t < NT - 2) { VMW8(); } else if (t == NT - 2) { VMW4(); } else { VMW0(); }
        BARRIER();
        const u16* Asl = As + (t & 3) * 4096;
        const u16* Bsl = Bs + (t & 3) * 4096;
        short8 bfr[4], afr[4];
#pragma unroll
        for (int n = 0; n < 4; ++n) {
            int row = wn * 64 + n * 16 + f;
            bfr[n] = *(const short8*)(Bsl + row * 32 + ((g ^ ((row >> 1) & 3)) << 3));
        }
#pragma unroll
        for (int m = 0; m < 4; ++m) {
            int row = wm * 64 + m * 16 + f;
            afr[m] = *(const short8*)(Asl + row * 32 + ((g ^ ((row >> 1) & 3)) << 3));
        }
        if (t + 3 < NT) {
            stage_tile128(A,  rowBase, Kdim, (t + 3) * 32, As + ((t + 3) & 3) * 4096, tid);
            stage_tile128(Bw, colBase, Kdim, (t + 3) * 32, Bs + ((t + 3) & 3) * 4096, tid);
        }
        __builtin_amdgcn_s_setprio(1);
#pragma unroll
        for (int m = 0; m < 4; ++m)
#pragma unroll
            for (int n = 0; n < 4; ++n)
                acc[m][n] = __builtin_amdgcn_mfma_f32_16x16x32_bf16(afr[m], bfr[n], acc[m][n], 0, 0, 0);
        __builtin_amdgcn_s_setprio(0);
    }

    int r0 = rowBase + wm * 64, c0 = colBase + wn * 64;
#pragma unroll
    for (int m = 0; m < 4; ++m) {
#pragma unroll
        for (int n = 0; n < 4; ++n) {
#pragma unroll
            for (int rg = 0; rg < 4; ++rg) {
                int gr = r0 + m * 16 + (lane >> 4) * 4 + rg;
                int gc = c0 + n * 16 + (lane & 15);
                size_t idx = (size_t)gr * Ndim + gc;
                float v = acc[m][n][rg];
                if (EPI == 2) Cf[idx] = aux1[idx] + v;
                else Cf[idx] = 1.f / (1.f + __expf(-v));
            }
        }
    }
}

// ================= WKV5 chunk-parallel scan =================
__device__ __forceinline__ size_t sidx(int b, int h, int c, int i, int j) {
    return ((((size_t)b * HH + h) * PCH + c) * NN + i) * NN + j;
}

__global__ __launch_bounds__(64) void wkv_p1(
    const float* __restrict__ k, const float* __restrict__ v,
    const float* __restrict__ decay, float* __restrict__ Sloc, int ld)
{
    int blk = blockIdx.x;
    int c  = blk & (PCH - 1);
    int jb = (blk >> 4) & 3;
    int h  = (blk >> 6) & (HH - 1);
    int b  = blk >> 10;
    int lane = threadIdx.x;
    int jj = lane & 15, g = lane >> 4;
    __shared__ float kbufS[64];
    float S[16], ew[16];
#pragma unroll
    for (int ii = 0; ii < 16; ++ii) {
        int i = g * 16 + ii;
        S[ii] = 0.f;
        ew[ii] = expf(-expf(decay[h * NN + i]));
    }
    const size_t base = ((size_t)b * TT + c * LCH) * ld + h * NN;
    const float* kb = k + base;
    const float* vb = v + base + jb * 16;

    for (int t = 0; t < LCH; ++t) {
        size_t off = (size_t)t * ld;
        float kv_ = kb[off + lane];
        float vv  = vb[off + jj];
        kbufS[lane] = kv_;
        __syncthreads();
        float4 kq[4];
#pragma unroll
        for (int q = 0; q < 4; ++q) kq[q] = ((const float4*)kbufS)[g * 4 + q];
        const float* kf = (const float*)kq;
#pragma unroll
        for (int ii = 0; ii < 16; ++ii)
            S[ii] = fmaf(ew[ii], S[ii], kf[ii] * vv);
        __syncthreads();
    }
#pragma unroll
    for (int ii = 0; ii < 16; ++ii)
        Sloc[sidx(b, h, c, g * 16 + ii, jb * 16 + jj)] = S[ii];
}

__global__ __launch_bounds__(64) void wkv_p2(
    const float* __restrict__ decay,
    const float* __restrict__ Sloc, float* __restrict__ Sst)
{
    int blk = blockIdx.x;           // B*H*4
    int jb = blk & 3;
    int h  = (blk >> 2) & (HH - 1);
    int b  = blk >> 6;
    int lane = threadIdx.x;
    int jj = lane & 15, g = lane >> 4;
    float Srun[16], ewL[16];
#pragma unroll
    for (int ii = 0; ii < 16; ++ii) {
        int i = g * 16 + ii;
        Srun[ii] = 0.f;
        ewL[ii] = expf(-expf(decay[h * NN + i]) * (float)LCH);
    }
    int j = jb * 16 + jj;
    for (int c = 0; c < PCH; ++c) {
#pragma unroll
        for (int ii = 0; ii < 16; ++ii) {
            size_t id = sidx(b, h, c, g * 16 + ii, j);
            Sst[id] = Srun[ii];
            Srun[ii] = fmaf(ewL[ii], Srun[ii], Sloc[id]);
        }
    }
}

// Phase 3 fused with GroupNorm + silu(g)-gate: block = (b,h,c), 4 warps = 4 jb.
__global__ __launch_bounds__(256) void wkv_p3g(
    const float* __restrict__ r, const float* __restrict__ k, const float* __restrict__ v,
    const float* __restrict__ decay, const float* __restrict__ u,
    const float* __restrict__ Sst, const float* __restrict__ gsil,
    const float* __restrict__ gw, const float* __restrict__ gb,
    u16* __restrict__ og, int ld)
{
    int blk = blockIdx.x;              // B*H*PCH = 1024
    int c = blk & (PCH - 1);
    int h = (blk >> 4) & (HH - 1);
    int b = blk >> 8;
    int tid = threadIdx.x;
    int jb = tid >> 6, lane = tid & 63;
    int jj = lane & 15, g = lane >> 4;
    __shared__ float rkbuf[128];
    __shared__ float ysh[64];
    float S[16], uu[16], ew[16];
    int j = jb * 16 + jj;
#pragma unroll
    for (int ii = 0; ii < 16; ++ii) {
        int i = g * 16 + ii;
        S[ii] = Sst[sidx(b, h, c, i, j)];
        ew[ii] = expf(-expf(decay[h * NN + i]));
        uu[ii] = u[h * NN + i];
    }
    const size_t base = ((size_t)b * TT + c * LCH) * ld + h * NN;
    const float* rb = r + base;
    const float* kb = k + base;
    const float* vb = v + base + jb * 16;
    float wv_ = gw[h * NN + lane];
    float bv_ = gb[h * NN + lane];
    const float* gsb = gsil + ((size_t)b * TT + c * LCH) * 4096 + h * NN;
    u16* ogb = og + ((size_t)b * TT + c * LCH) * CC + h * NN;

    for (int t = 0; t < LCH; ++t) {
        size_t off = (size_t)t * ld;
        float vv = vb[off + jj];
        if (jb == 0) {
            float rv  = rb[off + lane];
            float kv_ = kb[off + lane];
            rkbuf[2 * lane]     = rv;
            rkbuf[2 * lane + 1] = kv_;
        }
        __syncthreads();
        float acc = 0.f;
        const float2* rk2 = (const float2*)rkbuf;
#pragma unroll
        for (int ii = 0; ii < 16; ++ii) {
            float2 p = rk2[g * 16 + ii];
            float kvv = p.y * vv;
            float t1 = fmaf(uu[ii], kvv, S[ii]);
            acc = fmaf(p.x, t1, acc);
            S[ii] = fmaf(ew[ii], S[ii], kvv);
        }
        acc += __shfl_xor(acc, 16);
        acc += __shfl_xor(acc, 32);
        if (g == 0) ysh[jb * 16 + jj] = acc;
        __syncthreads();
        if (jb == 0) {
            float yv = ysh[lane] * 0.125f;
            float s = yv, ss = yv * yv;
#pragma unroll
            for (int m = 1; m < 64; m <<= 1) { s += __shfl_xor(s, m); ss += __shfl_xor(ss, m); }
            float mean = s * (1.f / NN);
            float var  = ss * (1.f / NN) - mean * mean;
            float inv  = rsqrtf(var + EPS_);
            float gv = gsb[(size_t)t * 4096 + lane];
            ogb[(size_t)t * CC + lane] = f2bf(((yv - mean) * inv * wv_ + bv_) * gv);
        }
        __syncthreads();
    }
}

// ---------------- split-K reduce + sigmoid-gate epilogue ----------------
__global__ __launch_bounds__(256) void reduce_cmv(const float* __restrict__ p,
    const float* __restrict__ x1, const float* __restrict__ sr, float* __restrict__ out)
{
    size_t i = ((size_t)blockIdx.x * 256 + threadIdx.x) * 4;
    const size_t stride = (size_t)MM * 1024;
    float4 a0 = *(const float4*)(p + i);
    float4 a1 = *(const float4*)(p + stride + i);
    float4 a2 = *(const float4*)(p + 2 * stride + i);
    float4 a3 = *(const float4*)(p + 3 * stride + i);
    float4 xv = *(const float4*)(x1 + i);
    float4 sv = *(const float4*)(sr + i);
    float4 o;
    o.x = xv.x + sv.x * (a0.x + a1.x + a2.x + a3.x);
    o.y = xv.y + sv.y * (a0.y + a1.y + a2.y + a3.y);
    o.z = xv.z + sv.z * (a0.z + a1.z + a2.z + a3.z);
    o.w = xv.w + sv.w * (a0.w + a1.w + a2.w + a3.w);
    *(float4*)(out + i) = o;
}

// ---------------- launcher ----------------
extern "C" void kernel_launch(void* const* d_in, const int* in_sizes, int n_in,
                              void* d_out, int out_size, void* d_ws, size_t ws_size,
                              hipStream_t stream)
{
    const float* x       = (const float*)d_in[0];
    const float* ln1_w   = (const float*)d_in[1];
    const float* ln1_b   = (const float*)d_in[2];
    const float* ln2_w   = (const float*)d_in[3];
    const float* ln2_b   = (const float*)d_in[4];
    const float* tm_mix_k= (const float*)d_in[5];
    const float* tm_mix_v= (const float*)d_in[6];
    const float* tm_mix_r= (const float*)d_in[7];
    const float* tm_mix_g= (const float*)d_in[8];
    const float* tm_decay= (const float*)d_in[9];
    const float* tm_u    = (const float*)d_in[10];
    const float* Wr      = (const float*)d_in[11];
    const float* Wk      = (const float*)d_in[12];
    const float* Wv      = (const float*)d_in[13];
    const float* Wg      = (const float*)d_in[14];
    const float* Wo      = (const float*)d_in[15];
    const float* lnx_w   = (const float*)d_in[16];
    const float* lnx_b   = (const float*)d_in[17];
    const float* cm_mix_k= (const float*)d_in[18];
    const float* cm_mix_r= (const float*)d_in[19];
    const float* cm_Wk   = (const float*)d_in[20];
    const float* cm_Wr   = (const float*)d_in[21];
    const float* cm_Wv   = (const float*)d_in[22];

    char* ws = (char*)d_ws;
    auto MB = [](size_t m) { return m * 1024ull * 1024ull; };
    u16*   z      = (u16*)(ws + 0);
    float* rkvg   = (float*)(ws + MB(16));
    float* partials = (float*)(ws + MB(16));
    float* sr     = (float*)(ws + MB(80));
    u16*   og     = (u16*)(ws + MB(96));
    u16*   xk     = (u16*)(ws + MB(96));
    u16*   xr     = (u16*)(ws + MB(104));
    float* Sloc   = (float*)(ws + MB(112));
    float* x1     = (float*)(ws + MB(112));
    u16*   W4p    = (u16*)(ws + MB(128));
    float* Sst    = (float*)(ws + MB(128));
    u16*   kbuf2  = (u16*)(ws + MB(128));
    u16*   Wo_b   = (u16*)(ws + MB(160));
    u16*   cmWk_b = (u16*)(ws + MB(162));
    u16*   cmWr_b = (u16*)(ws + MB(170));
    u16*   cmWv_b = (u16*)(ws + MB(172));
    // NOTE: Sloc@112 dead before x1 write (step 7); Sst@128 written after W4p's last
    // use (step 3) and read before kbuf2 write (step 9); og@96 consumed (step 7)
    // before xk overwrite (step 8).

    // 1. merged weight prep (one launch)
    PrepArgs pa;
    pa.Wr = Wr; pa.Wk = Wk; pa.Wv = Wv; pa.Wg = Wg;
    pa.mr = tm_mix_r; pa.mk = tm_mix_k; pa.mv = tm_mix_v; pa.mg = tm_mix_g;
    pa.W4p = W4p;
    pa.csrc[0] = Wo;    pa.cdst[0] = Wo_b;
    pa.csrc[1] = cm_Wk; pa.cdst[1] = cmWk_b;
    pa.csrc[2] = cm_Wr; pa.cdst[2] = cmWr_b;
    pa.csrc[3] = cm_Wv; pa.cdst[3] = cmWv_b;
    int q = (CC * CC) / 4;   // 262144
    pa.cstart4[0] = 0; pa.cstart4[1] = q; pa.cstart4[2] = 5 * q; pa.cstart4[3] = 6 * q;
    pa.ctotal4 = 10 * q;
    prep_kernel<<<4096 + (10 * q + 255) / 256, 256, 0, stream>>>(pa);

    // 2. LN1 -> z1 (concat bf16)
    lnz_kernel<<<MM, 256, 0, stream>>>(x, ln1_w, ln1_b, z);

    // 3. merged r|k|v|g projection: rkvg = z1 @ W4p^T (silu on g cols)
    gemm8<6><<<dim3(16, 16, 1), 512, 0, stream>>>(z, W4p, rkvg, nullptr, MM, 4096, 2048, 2048);

    // 4. WKV5 chunk-parallel scan (strided over rkvg); p3 fused with GN+gate -> og
    wkv_p1<<<BB * HH * 4 * PCH, 64, 0, stream>>>(rkvg + 1024, rkvg + 2048, tm_decay, Sloc, 4096);
    wkv_p2<<<BB * HH * 4, 64, 0, stream>>>(tm_decay, Sloc, Sst);
    wkv_p3g<<<BB * HH * PCH, 256, 0, stream>>>(rkvg, rkvg + 1024, rkvg + 2048,
                                               tm_decay, tm_u, Sst, rkvg + 3072,
                                               lnx_w, lnx_b, og, 4096);

    // 6. x1 = x + og @ Wo^T  (ring-pipelined 128^2)
    dim3 gr1(CC / 128, MM / 128);
    gemmr<2><<<gr1, 256, 0, stream>>>(og, Wo_b, x1, x, MM, CC, CC);

    // 7. fused LN2 + channel-mix -> xk, xr (bf16)
    ln2m_kernel<<<MM, 256, 0, stream>>>(x1, ln2_w, ln2_b, cm_mix_k, cm_mix_r, xk, xr);

    // 8. kbuf2 = relu(xk @ cm_Wk^T)^2 bf16 ; sr = sigmoid(xr @ cm_Wr^T)
    gemm8<3><<<dim3(16, 16, 1), 512, 0, stream>>>(xk, cmWk_b, nullptr, kbuf2, MM, 4096, 1024, 1024);
    gemmr<4><<<gr1, 256, 0, stream>>>(xr, cmWr_b, sr, nullptr, MM, CC, CC);

    // 9. split-K=4: partials[z] = kbuf2[:, z*1024:(z+1)*1024] @ cm_Wv[:, same]^T
    gemm8<7><<<dim3(4, 16, 4), 512, 0, stream>>>(kbuf2, cmWv_b, partials, nullptr, MM, 1024, 4096, 1024);

    // 10. out = x1 + sr * sum(partials)
    reduce_cmv<<<4096, 256, 0, stream>>>(partials, x1, sr, (float*)d_out);
}

// Round 10
// 457.637 us; speedup vs baseline: 1.0441x; 1.0441x over previous
//
#include <hip/hip_runtime.h>
#include <stdint.h>

typedef unsigned short u16;
typedef __attribute__((ext_vector_type(8))) short short8;
typedef __attribute__((ext_vector_type(4))) float f32x4;

#define BB 4
#define TT 1024
#define CC 1024
#define HH 16
#define NN 64
#define MM (BB*TT)        // 4096 rows
#define FFN_ 4096
#define PCH 16            // WKV chunks
#define LCH (TT/PCH)      // 64 steps per chunk
static constexpr float EPS_ = 1e-5f;

__device__ __forceinline__ u16 f2bf(float f) {
    union { float f; uint32_t u; } x; x.f = f;
    uint32_t r = x.u + 0x7fff + ((x.u >> 16) & 1);   // RNE
    return (u16)(r >> 16);
}
__device__ __forceinline__ float bf2f(u16 b) {
    union { uint32_t u; float f; } x; x.u = ((uint32_t)b) << 16; return x.f;
}

#define VMW8() asm volatile("s_waitcnt vmcnt(8)" ::: "memory")
#define VMW4() asm volatile("s_waitcnt vmcnt(4)" ::: "memory")
#define VMW0() asm volatile("s_waitcnt vmcnt(0)" ::: "memory")
#define BARRIER() do { asm volatile("" ::: "memory"); __builtin_amdgcn_s_barrier(); asm volatile("" ::: "memory"); } while (0)

// ---------------- LayerNorm -> concat-bf16 z (LN1 only) ----------------
__global__ __launch_bounds__(256) void lnz_kernel(const float* __restrict__ x,
    const float* __restrict__ w, const float* __restrict__ b, u16* __restrict__ z)
{
    int row = blockIdx.x;
    int tid = threadIdx.x;
    const float* xr = x + (size_t)row * CC;
    float4 v = ((const float4*)xr)[tid];
    float s  = v.x + v.y + v.z + v.w;
    float ss = v.x*v.x + v.y*v.y + v.z*v.z + v.w*v.w;
#pragma unroll
    for (int m = 1; m < 64; m <<= 1) { s += __shfl_xor(s, m); ss += __shfl_xor(ss, m); }
    __shared__ float as_[4], bs_[4];
    int wv = tid >> 6, ln = tid & 63;
    if (ln == 0) { as_[wv] = s; bs_[wv] = ss; }
    __syncthreads();
    s  = as_[0] + as_[1] + as_[2] + as_[3];
    ss = bs_[0] + bs_[1] + bs_[2] + bs_[3];
    float mean = s * (1.f / CC);
    float var  = ss * (1.f / CC) - mean * mean;
    float inv  = rsqrtf(var + EPS_);
    float4 w4 = ((const float4*)w)[tid];
    float4 b4 = ((const float4*)b)[tid];
    ushort4 o;
    o.x = f2bf((v.x - mean) * inv * w4.x + b4.x);
    o.y = f2bf((v.y - mean) * inv * w4.y + b4.y);
    o.z = f2bf((v.z - mean) * inv * w4.z + b4.z);
    o.w = f2bf((v.w - mean) * inv * w4.w + b4.w);
    int t = row & (TT - 1);
    *(ushort4*)(z + (size_t)row * 2048 + tid * 4) = o;
    if (t < TT - 1) *(ushort4*)(z + (size_t)(row + 1) * 2048 + 1024 + tid * 4) = o;
    if (t == 0) {
        ushort4 zz; zz.x = 0; zz.y = 0; zz.z = 0; zz.w = 0;
        *(ushort4*)(z + (size_t)row * 2048 + 1024 + tid * 4) = zz;
    }
}

// ---------------- fused LN2 + channel-mix: x1 -> xk, xr (bf16) ----------------
__global__ __launch_bounds__(256) void ln2m_kernel(const float* __restrict__ x1,
    const float* __restrict__ w, const float* __restrict__ b,
    const float* __restrict__ mk, const float* __restrict__ mr,
    u16* __restrict__ xk, u16* __restrict__ xr)
{
    int row = blockIdx.x;
    int tid = threadIdx.x;
    int t = row & (TT - 1);
    float4 vc = ((const float4*)(x1 + (size_t)row * CC))[tid];
    float4 vp = make_float4(0.f, 0.f, 0.f, 0.f);
    if (t) vp = ((const float4*)(x1 + (size_t)(row - 1) * CC))[tid];
    float sc  = vc.x + vc.y + vc.z + vc.w;
    float ssc = vc.x*vc.x + vc.y*vc.y + vc.z*vc.z + vc.w*vc.w;
    float sp  = vp.x + vp.y + vp.z + vp.w;
    float ssp = vp.x*vp.x + vp.y*vp.y + vp.z*vp.z + vp.w*vp.w;
#pragma unroll
    for (int m = 1; m < 64; m <<= 1) {
        sc += __shfl_xor(sc, m); ssc += __shfl_xor(ssc, m);
        sp += __shfl_xor(sp, m); ssp += __shfl_xor(ssp, m);
    }
    __shared__ float red[4][4];
    int wv = tid >> 6, ln = tid & 63;
    if (ln == 0) { red[wv][0] = sc; red[wv][1] = ssc; red[wv][2] = sp; red[wv][3] = ssp; }
    __syncthreads();
    sc  = red[0][0] + red[1][0] + red[2][0] + red[3][0];
    ssc = red[0][1] + red[1][1] + red[2][1] + red[3][1];
    sp  = red[0][2] + red[1][2] + red[2][2] + red[3][2];
    ssp = red[0][3] + red[1][3] + red[2][3] + red[3][3];
    float mc = sc * (1.f / CC);
    float invc = rsqrtf(ssc * (1.f / CC) - mc * mc + EPS_);
    float mp = sp * (1.f / CC);
    float invp = rsqrtf(ssp * (1.f / CC) - mp * mp + EPS_);
    float4 w4 = ((const float4*)w)[tid];
    float4 b4 = ((const float4*)b)[tid];
    int c = tid << 2;
    float4 k4 = *(const float4*)(mk + c);
    float4 r4 = *(const float4*)(mr + c);
    float lc0 = (vc.x - mc) * invc * w4.x + b4.x;
    float lc1 = (vc.y - mc) * invc * w4.y + b4.y;
    float lc2 = (vc.z - mc) * invc * w4.z + b4.z;
    float lc3 = (vc.w - mc) * invc * w4.w + b4.w;
    float lp0 = t ? (vp.x - mp) * invp * w4.x + b4.x : 0.f;
    float lp1 = t ? (vp.y - mp) * invp * w4.y + b4.y : 0.f;
    float lp2 = t ? (vp.z - mp) * invp * w4.z + b4.z : 0.f;
    float lp3 = t ? (vp.w - mp) * invp * w4.w + b4.w : 0.f;
    ushort4 ok, orr;
    ok.x  = f2bf(lp0 + k4.x * (lc0 - lp0)); ok.y  = f2bf(lp1 + k4.y * (lc1 - lp1));
    ok.z  = f2bf(lp2 + k4.z * (lc2 - lp2)); ok.w  = f2bf(lp3 + k4.w * (lc3 - lp3));
    orr.x = f2bf(lp0 + r4.x * (lc0 - lp0)); orr.y = f2bf(lp1 + r4.y * (lc1 - lp1));
    orr.z = f2bf(lp2 + r4.z * (lc2 - lp2)); orr.w = f2bf(lp3 + r4.w * (lc3 - lp3));
    size_t f = (size_t)row * 1024 + c;
    *(ushort4*)(xk + f) = ok;
    *(ushort4*)(xr + f) = orr;
}

// ---------------- merged weight prep: W4 build + 4 bf16 conversions, ONE launch ----------------
struct PrepArgs {
    const float *Wr, *Wk, *Wv, *Wg, *mr, *mk, *mv, *mg;
    u16* W4p;
    const float* csrc[4];
    u16* cdst[4];
    int cstart4[4];    // {0, q, 5q, 6q}
    int ctotal4;       // 10q
};
__global__ __launch_bounds__(256) void prep_kernel(PrepArgs a)
{
    int bid = blockIdx.x;
    if (bid < 4096) {
        int idx = bid * 256 + threadIdx.x;
        int n = idx >> 8, c = (idx & 255) << 2;
        int sel = n >> 10, nr = n & 1023;
        const float* W = sel == 0 ? a.Wr : sel == 1 ? a.Wk : sel == 2 ? a.Wv : a.Wg;
        const float* mx = sel == 0 ? a.mr : sel == 1 ? a.mk : sel == 2 ? a.mv : a.mg;
        float4 w4 = *(const float4*)(W + (size_t)nr * 1024 + c);
        float4 m4 = *(const float4*)(mx + c);
        ushort4 p, q4;
        p.x  = f2bf(w4.x * m4.x); p.y  = f2bf(w4.y * m4.y);
        p.z  = f2bf(w4.z * m4.z); p.w  = f2bf(w4.w * m4.w);
        q4.x = f2bf(w4.x * (1.f - m4.x)); q4.y = f2bf(w4.y * (1.f - m4.y));
        q4.z = f2bf(w4.z * (1.f - m4.z)); q4.w = f2bf(w4.w * (1.f - m4.w));
        *(ushort4*)(a.W4p + (size_t)n * 2048 + c) = p;
        *(ushort4*)(a.W4p + (size_t)n * 2048 + 1024 + c) = q4;
    } else {
        int i4 = (bid - 4096) * 256 + threadIdx.x;
        if (i4 >= a.ctotal4) return;
        int s = 0;
#pragma unroll
        for (int j = 1; j < 4; ++j) if (i4 >= a.cstart4[j]) s = j;
        int l4 = i4 - a.cstart4[s];
        float4 v = ((const float4*)a.csrc[s])[l4];
        ushort4 o; o.x = f2bf(v.x); o.y = f2bf(v.y); o.z = f2bf(v.z); o.w = f2bf(v.w);
        ((ushort4*)a.cdst[s])[l4] = o;
    }
}

// ================ 256x256-tile ring-4 bf16 GEMM (r3-proven schedule) ================
__device__ __forceinline__ void stage_tile(const u16* gbase, int rbase, int ldk,
                                           int kcol, u16* ldsbase, int tid)
{
#pragma unroll
    for (int rd = 0; rd < 2; ++rd) {
        int row = rd * 128 + (tid >> 2);
        int slog = (tid & 3) ^ ((row >> 1) & 3);           // T2 pre-swizzled source
        const u16* src = gbase + (size_t)(rbase + row) * ldk + kcol + (slog << 3);
        u16* dst = ldsbase + row * 32 + ((tid & 3) << 3);  // linear dest
        __builtin_amdgcn_global_load_lds(
            (const __attribute__((address_space(1))) uint32_t*)(const void*)src,
            (__attribute__((address_space(3))) uint32_t*)(void*)dst, 16, 0, 0);
    }
}

// EPI: 3 relu(v)^2 -> bf16 | 6 rkvg (silu for cols>=3072) | 7 split-K partial f32
template<int EPI>
__global__ __launch_bounds__(512, 2) void gemm8(
    const u16* __restrict__ A, const u16* __restrict__ Bw,
    float* __restrict__ Cf, u16* __restrict__ Cbf,
    int Mdim, int Ndim, int Kdim, int kLen)
{
    __shared__ u16 As[4 * 8192];
    __shared__ u16 Bs[4 * 8192];
    int tid = threadIdx.x;
    int wid = tid >> 6, lane = tid & 63;
    int wm = wid >> 2, wn = wid & 3;
    int f = lane & 15, g = lane >> 4;

    int nwg = gridDim.x * gridDim.y;
    int bid = blockIdx.y * gridDim.x + blockIdx.x;
    int qq = nwg >> 3, r8 = nwg & 7;
    int xcd = bid & 7, lid = bid >> 3;
    int swz = (xcd < r8 ? xcd * (qq + 1) : r8 * (qq + 1) + (xcd - r8) * qq) + lid;
    int bx = swz % gridDim.x, by = swz / gridDim.x;
    int rowBase = by * 256, colBase = bx * 256;
    int kOff = blockIdx.z * kLen;
    int NT = kLen >> 5;
    if (EPI == 7) Cf += (size_t)blockIdx.z * Mdim * Ndim;

    f32x4 acc[8][4] = {};

    stage_tile(A,  rowBase, Kdim, kOff,      As, tid);
    stage_tile(Bw, colBase, Kdim, kOff,      Bs, tid);
    if (NT > 1) {
        stage_tile(A,  rowBase, Kdim, kOff + 32, As + 8192, tid);
        stage_tile(Bw, colBase, Kdim, kOff + 32, Bs + 8192, tid);
    }
    if (NT > 2) {
        stage_tile(A,  rowBase, Kdim, kOff + 64, As + 2 * 8192, tid);
        stage_tile(Bw, colBase, Kdim, kOff + 64, Bs + 2 * 8192, tid);
    }

    for (int t = 0; t < NT; ++t) {
        if (t < NT - 2) { VMW8(); } else if (t == NT - 2) { VMW4(); } else { VMW0(); }
        BARRIER();
        const u16* Asl = As + (t & 3) * 8192;
        const u16* Bsl = Bs + (t & 3) * 8192;
        short8 bfr[4], afr[4];
#pragma unroll
        for (int n = 0; n < 4; ++n) {
            int row = wn * 64 + n * 16 + f;
            bfr[n] = *(const short8*)(Bsl + row * 32 + ((g ^ ((row >> 1) & 3)) << 3));
        }
#pragma unroll
        for (int m = 0; m < 4; ++m) {
            int row = wm * 128 + m * 16 + f;
            afr[m] = *(const short8*)(Asl + row * 32 + ((g ^ ((row >> 1) & 3)) << 3));
        }
        if (t + 3 < NT)
            stage_tile(A, rowBase, Kdim, kOff + (t + 3) * 32, As + ((t + 3) & 3) * 8192, tid);
        __builtin_amdgcn_s_setprio(1);
#pragma unroll
        for (int m = 0; m < 4; ++m)
#pragma unroll
            for (int n = 0; n < 4; ++n)
                acc[m][n] = __builtin_amdgcn_mfma_f32_16x16x32_bf16(afr[m], bfr[n], acc[m][n], 0, 0, 0);
        __builtin_amdgcn_s_setprio(0);
#pragma unroll
        for (int m = 0; m < 4; ++m) {
            int row = wm * 128 + 64 + m * 16 + f;
            afr[m] = *(const short8*)(Asl + row * 32 + ((g ^ ((row >> 1) & 3)) << 3));
        }
        if (t + 3 < NT)
            stage_tile(Bw, colBase, Kdim, kOff + (t + 3) * 32, Bs + ((t + 3) & 3) * 8192, tid);
        __builtin_amdgcn_s_setprio(1);
#pragma unroll
        for (int m = 0; m < 4; ++m)
#pragma unroll
            for (int n = 0; n < 4; ++n)
                acc[4 + m][n] = __builtin_amdgcn_mfma_f32_16x16x32_bf16(afr[m], bfr[n], acc[4 + m][n], 0, 0, 0);
        __builtin_amdgcn_s_setprio(0);
    }

    int r0 = rowBase + wm * 128, c0 = colBase + wn * 64;
    bool dsilu = (EPI == 6) && (colBase >= 3072);
#pragma unroll
    for (int am = 0; am < 8; ++am) {
#pragma unroll
        for (int n = 0; n < 4; ++n) {
#pragma unroll
            for (int rg = 0; rg < 4; ++rg) {
                int gr = r0 + am * 16 + (lane >> 4) * 4 + rg;
                int gc = c0 + n * 16 + (lane & 15);
                size_t idx = (size_t)gr * Ndim + gc;
                float v = acc[am][n][rg];
                if (EPI == 3) { float rr = v > 0.f ? v : 0.f; Cbf[idx] = f2bf(rr * rr); }
                else if (EPI == 6) Cf[idx] = dsilu ? v / (1.f + __expf(-v)) : v;
                else Cf[idx] = v;
            }
        }
    }
}

// ================ 128x128-tile ring-4 bf16 GEMM for N=1024 shapes ================
__device__ __forceinline__ void stage_tile128(const u16* gbase, int rbase, int ldk,
                                              int kcol, u16* ldsbase, int tid)
{
#pragma unroll
    for (int rd = 0; rd < 2; ++rd) {
        int row = rd * 64 + (tid >> 2);
        int slog = (tid & 3) ^ ((row >> 1) & 3);
        const u16* src = gbase + (size_t)(rbase + row) * ldk + kcol + (slog << 3);
        u16* dst = ldsbase + row * 32 + ((tid & 3) << 3);
        __builtin_amdgcn_global_load_lds(
            (const __attribute__((address_space(1))) uint32_t*)(const void*)src,
            (__attribute__((address_space(3))) uint32_t*)(void*)dst, 16, 0, 0);
    }
}

// EPI: 2 aux1+v f32 | 4 sigmoid f32
template<int EPI>
__global__ __launch_bounds__(256, 2) void gemmr(
    const u16* __restrict__ A, const u16* __restrict__ Bw,
    float* __restrict__ Cf,
    const float* __restrict__ aux1,
    int Mdim, int Ndim, int Kdim)
{
    __shared__ u16 As[4 * 4096];   // 32 KiB
    __shared__ u16 Bs[4 * 4096];   // 32 KiB
    int tid = threadIdx.x;
    int wid = tid >> 6, lane = tid & 63;
    int wm = wid >> 1, wn = wid & 1;
    int f = lane & 15, g = lane >> 4;

    int nwg = gridDim.x * gridDim.y;
    int bid = blockIdx.y * gridDim.x + blockIdx.x;
    int qq = nwg >> 3, r8 = nwg & 7;
    int xcd = bid & 7, lid = bid >> 3;
    int swz = (xcd < r8 ? xcd * (qq + 1) : r8 * (qq + 1) + (xcd - r8) * qq) + lid;
    int bx = swz % gridDim.x, by = swz / gridDim.x;
    int rowBase = by * 128, colBase = bx * 128;
    int NT = Kdim >> 5;

    f32x4 acc[4][4] = {};

    stage_tile128(A,  rowBase, Kdim, 0,  As, tid);
    stage_tile128(Bw, colBase, Kdim, 0,  Bs, tid);
    stage_tile128(A,  rowBase, Kdim, 32, As + 4096, tid);
    stage_tile128(Bw, colBase, Kdim, 32, Bs + 4096, tid);
    stage_tile128(A,  rowBase, Kdim, 64, As + 2 * 4096, tid);
    stage_tile128(Bw, colBase, Kdim, 64, Bs + 2 * 4096, tid);

    for (int t = 0; t < NT; ++t) {
        if (t < NT - 2) { VMW8(); } else if (t == NT - 2) { VMW4(); } else { VMW0(); }
        BARRIER();
        const u16* Asl = As + (t & 3) * 4096;
        const u16* Bsl = Bs + (t & 3) * 4096;
        short8 bfr[4], afr[4];
#pragma unroll
        for (int n = 0; n < 4; ++n) {
            int row = wn * 64 + n * 16 + f;
            bfr[n] = *(const short8*)(Bsl + row * 32 + ((g ^ ((row >> 1) & 3)) << 3));
        }
#pragma unroll
        for (int m = 0; m < 4; ++m) {
            int row = wm * 64 + m * 16 + f;
            afr[m] = *(const short8*)(Asl + row * 32 + ((g ^ ((row >> 1) & 3)) << 3));
        }
        if (t + 3 < NT) {
            stage_tile128(A,  rowBase, Kdim, (t + 3) * 32, As + ((t + 3) & 3) * 4096, tid);
            stage_tile128(Bw, colBase, Kdim, (t + 3) * 32, Bs + ((t + 3) & 3) * 4096, tid);
        }
        __builtin_amdgcn_s_setprio(1);
#pragma unroll
        for (int m = 0; m < 4; ++m)
#pragma unroll
            for (int n = 0; n < 4; ++n)
                acc[m][n] = __builtin_amdgcn_mfma_f32_16x16x32_bf16(afr[m], bfr[n], acc[m][n], 0, 0, 0);
        __builtin_amdgcn_s_setprio(0);
    }

    int r0 = rowBase + wm * 64, c0 = colBase + wn * 64;
#pragma unroll
    for (int m = 0; m < 4; ++m) {
#pragma unroll
        for (int n = 0; n < 4; ++n) {
#pragma unroll
            for (int rg = 0; rg < 4; ++rg) {
                int gr = r0 + m * 16 + (lane >> 4) * 4 + rg;
                int gc = c0 + n * 16 + (lane & 15);
                size_t idx = (size_t)gr * Ndim + gc;
                float v = acc[m][n][rg];
                if (EPI == 2) Cf[idx] = aux1[idx] + v;
                else Cf[idx] = 1.f / (1.f + __expf(-v));
            }
        }
    }
}

// ================= WKV5 chunk-parallel scan =================
__device__ __forceinline__ size_t sidx(int b, int h, int c, int i, int j) {
    return ((((size_t)b * HH + h) * PCH + c) * NN + i) * NN + j;
}

__global__ __launch_bounds__(64) void wkv_p1(
    const float* __restrict__ k, const float* __restrict__ v,
    const float* __restrict__ decay, float* __restrict__ Sloc, int ld)
{
    int blk = blockIdx.x;
    int c  = blk & (PCH - 1);
    int jb = (blk >> 4) & 3;
    int h  = (blk >> 6) & (HH - 1);
    int b  = blk >> 10;
    int lane = threadIdx.x;
    int jj = lane & 15, g = lane >> 4;
    __shared__ float kbufS[64];
    float S[16], ew[16];
#pragma unroll
    for (int ii = 0; ii < 16; ++ii) {
        int i = g * 16 + ii;
        S[ii] = 0.f;
        ew[ii] = expf(-expf(decay[h * NN + i]));
    }
    const size_t base = ((size_t)b * TT + c * LCH) * ld + h * NN;
    const float* kb = k + base;
    const float* vb = v + base + jb * 16;

    for (int t = 0; t < LCH; ++t) {
        size_t off = (size_t)t * ld;
        float kv_ = kb[off + lane];
        float vv  = vb[off + jj];
        kbufS[lane] = kv_;
        __syncthreads();
        float4 kq[4];
#pragma unroll
        for (int q = 0; q < 4; ++q) kq[q] = ((const float4*)kbufS)[g * 4 + q];
        const float* kf = (const float*)kq;
#pragma unroll
        for (int ii = 0; ii < 16; ++ii)
            S[ii] = fmaf(ew[ii], S[ii], kf[ii] * vv);
        __syncthreads();
    }
#pragma unroll
    for (int ii = 0; ii < 16; ++ii)
        Sloc[sidx(b, h, c, g * 16 + ii, jb * 16 + jj)] = S[ii];
}

__global__ __launch_bounds__(64) void wkv_p2(
    const float* __restrict__ decay,
    const float* __restrict__ Sloc, float* __restrict__ Sst)
{
    int blk = blockIdx.x;           // B*H*4
    int jb = blk & 3;
    int h  = (blk >> 2) & (HH - 1);
    int b  = blk >> 6;
    int lane = threadIdx.x;
    int jj = lane & 15, g = lane >> 4;
    float Srun[16], ewL[16];
#pragma unroll
    for (int ii = 0; ii < 16; ++ii) {
        int i = g * 16 + ii;
        Srun[ii] = 0.f;
        ewL[ii] = expf(-expf(decay[h * NN + i]) * (float)LCH);
    }
    int j = jb * 16 + jj;
    for (int c = 0; c < PCH; ++c) {
#pragma unroll
        for (int ii = 0; ii < 16; ++ii) {
            size_t id = sidx(b, h, c, g * 16 + ii, j);
            Sst[id] = Srun[ii];
            Srun[ii] = fmaf(ewL[ii], Srun[ii], Sloc[id]);
        }
    }
}

__global__ __launch_bounds__(64) void wkv_p3(
    const float* __restrict__ r, const float* __restrict__ k, const float* __restrict__ v,
    const float* __restrict__ decay, const float* __restrict__ u,
    const float* __restrict__ Sst, float* __restrict__ y, int ld)
{
    int blk = blockIdx.x;
    int c  = blk & (PCH - 1);
    int jb = (blk >> 4) & 3;
    int h  = (blk >> 6) & (HH - 1);
    int b  = blk >> 10;
    int lane = threadIdx.x;
    int jj = lane & 15, g = lane >> 4;
    __shared__ float rkbuf[128];
    float S[16], uu[16], ew[16];
#pragma unroll
    for (int ii = 0; ii < 16; ++ii) {
        int i = g * 16 + ii;
        S[ii] = Sst[sidx(b, h, c, i, jb * 16 + jj)];
        ew[ii] = expf(-expf(decay[h * NN + i]));
        uu[ii] = u[h * NN + i];
    }
    const size_t base = ((size_t)b * TT + c * LCH) * ld + h * NN;
    const float* rb = r + base;
    const float* kb = k + base;
    const float* vb = v + base + jb * 16;
    float* yb = y + (((size_t)b * TT + c * LCH)) * CC + h * NN + jb * 16;

    for (int t = 0; t < LCH; ++t) {
        size_t off = (size_t)t * ld;
        float rv  = rb[off + lane];
        float kv_ = kb[off + lane];
        float vv  = vb[off + jj];
        rkbuf[2 * lane]     = rv;
        rkbuf[2 * lane + 1] = kv_;
        __syncthreads();
        float acc = 0.f;
        const float2* rk2 = (const float2*)rkbuf;
#pragma unroll
        for (int ii = 0; ii < 16; ++ii) {
            float2 p = rk2[g * 16 + ii];
            float kvv = p.y * vv;
            float t1 = fmaf(uu[ii], kvv, S[ii]);
            acc = fmaf(p.x, t1, acc);
            S[ii] = fmaf(ew[ii], S[ii], kvv);
        }
        acc += __shfl_xor(acc, 16);
        acc += __shfl_xor(acc, 32);
        if (g == 0) yb[(size_t)t * CC + jj] = acc;
        __syncthreads();
    }
}

// ---------------- GroupNorm(y/8)*w+b, * silu(g) [pre-applied], -> bf16 ----------------
__global__ __launch_bounds__(256) void gn_kernel(const float* __restrict__ y,
    const float* __restrict__ gsil, const float* __restrict__ w, const float* __restrict__ b,
    u16* __restrict__ og)
{
    int row = blockIdx.x;
    int tid = threadIdx.x;
    int head = tid >> 4, q = tid & 15;
    int cb = head * NN + q * 4;
    size_t base = (size_t)row * CC + cb;
    float4 v = *(const float4*)(y + base);
    v.x *= 0.125f; v.y *= 0.125f; v.z *= 0.125f; v.w *= 0.125f;
    float s  = v.x + v.y + v.z + v.w;
    float ss = v.x*v.x + v.y*v.y + v.z*v.z + v.w*v.w;
#pragma unroll
    for (int m = 1; m < 16; m <<= 1) { s += __shfl_xor(s, m); ss += __shfl_xor(ss, m); }
    float mean = s * (1.f / NN);
    float var  = ss * (1.f / NN) - mean * mean;
    float inv  = rsqrtf(var + EPS_);
    float4 w4 = *(const float4*)(w + cb);
    float4 b4 = *(const float4*)(b + cb);
    float4 g4 = *(const float4*)(gsil + (size_t)row * 4096 + cb);
    ushort4 o;
    o.x = f2bf(((v.x - mean) * inv * w4.x + b4.x) * g4.x);
    o.y = f2bf(((v.y - mean) * inv * w4.y + b4.y) * g4.y);
    o.z = f2bf(((v.z - mean) * inv * w4.z + b4.z) * g4.z);
    o.w = f2bf(((v.w - mean) * inv * w4.w + b4.w) * g4.w);
    *(ushort4*)(og + base) = o;
}

// ---------------- split-K reduce + sigmoid-gate epilogue ----------------
__global__ __launch_bounds__(256) void reduce_cmv(const float* __restrict__ p,
    const float* __restrict__ x1, const float* __restrict__ sr, float* __restrict__ out)
{
    size_t i = ((size_t)blockIdx.x * 256 + threadIdx.x) * 4;
    const size_t stride = (size_t)MM * 1024;
    float4 a0 = *(const float4*)(p + i);
    float4 a1 = *(const float4*)(p + stride + i);
    float4 a2 = *(const float4*)(p + 2 * stride + i);
    float4 a3 = *(const float4*)(p + 3 * stride + i);
    float4 xv = *(const float4*)(x1 + i);
    float4 sv = *(const float4*)(sr + i);
    float4 o;
    o.x = xv.x + sv.x * (a0.x + a1.x + a2.x + a3.x);
    o.y = xv.y + sv.y * (a0.y + a1.y + a2.y + a3.y);
    o.z = xv.z + sv.z * (a0.z + a1.z + a2.z + a3.z);
    o.w = xv.w + sv.w * (a0.w + a1.w + a2.w + a3.w);
    *(float4*)(out + i) = o;
}

// ---------------- launcher ----------------
extern "C" void kernel_launch(void* const* d_in, const int* in_sizes, int n_in,
                              void* d_out, int out_size, void* d_ws, size_t ws_size,
                              hipStream_t stream)
{
    const float* x       = (const float*)d_in[0];
    const float* ln1_w   = (const float*)d_in[1];
    const float* ln1_b   = (const float*)d_in[2];
    const float* ln2_w   = (const float*)d_in[3];
    const float* ln2_b   = (const float*)d_in[4];
    const float* tm_mix_k= (const float*)d_in[5];
    const float* tm_mix_v= (const float*)d_in[6];
    const float* tm_mix_r= (const float*)d_in[7];
    const float* tm_mix_g= (const float*)d_in[8];
    const float* tm_decay= (const float*)d_in[9];
    const float* tm_u    = (const float*)d_in[10];
    const float* Wr      = (const float*)d_in[11];
    const float* Wk      = (const float*)d_in[12];
    const float* Wv      = (const float*)d_in[13];
    const float* Wg      = (const float*)d_in[14];
    const float* Wo      = (const float*)d_in[15];
    const float* lnx_w   = (const float*)d_in[16];
    const float* lnx_b   = (const float*)d_in[17];
    const float* cm_mix_k= (const float*)d_in[18];
    const float* cm_mix_r= (const float*)d_in[19];
    const float* cm_Wk   = (const float*)d_in[20];
    const float* cm_Wr   = (const float*)d_in[21];
    const float* cm_Wv   = (const float*)d_in[22];

    char* ws = (char*)d_ws;
    auto MB = [](size_t m) { return m * 1024ull * 1024ull; };
    u16*   z      = (u16*)(ws + 0);
    float* rkvg   = (float*)(ws + MB(16));
    float* partials = (float*)(ws + MB(16));
    float* ybuf   = (float*)(ws + MB(80));
    float* sr     = (float*)(ws + MB(80));
    u16*   og     = (u16*)(ws + MB(96));
    u16*   xk     = (u16*)(ws + MB(96));
    u16*   xr     = (u16*)(ws + MB(104));
    float* Sloc   = (float*)(ws + MB(112));
    float* x1     = (float*)(ws + MB(112));
    u16*   W4p    = (u16*)(ws + MB(128));
    float* Sst    = (float*)(ws + MB(128));
    u16*   kbuf2  = (u16*)(ws + MB(128));
    u16*   Wo_b   = (u16*)(ws + MB(160));
    u16*   cmWk_b = (u16*)(ws + MB(162));
    u16*   cmWr_b = (u16*)(ws + MB(170));
    u16*   cmWv_b = (u16*)(ws + MB(172));
    // Liveness: ybuf@80 (p3 write, gn read) dead before sr write (step 8);
    // Sloc@112 dead before x1 write (step 6); Sst@128 written after W4p's last
    // use (step 3), read before kbuf2 write (step 8); og@96 consumed (step 6)
    // before xk overwrite (step 7).

    // 1. merged weight prep (one launch)
    PrepArgs pa;
    pa.Wr = Wr; pa.Wk = Wk; pa.Wv = Wv; pa.Wg = Wg;
    pa.mr = tm_mix_r; pa.mk = tm_mix_k; pa.mv = tm_mix_v; pa.mg = tm_mix_g;
    pa.W4p = W4p;
    pa.csrc[0] = Wo;    pa.cdst[0] = Wo_b;
    pa.csrc[1] = cm_Wk; pa.cdst[1] = cmWk_b;
    pa.csrc[2] = cm_Wr; pa.cdst[2] = cmWr_b;
    pa.csrc[3] = cm_Wv; pa.cdst[3] = cmWv_b;
    int q = (CC * CC) / 4;   // 262144
    pa.cstart4[0] = 0; pa.cstart4[1] = q; pa.cstart4[2] = 5 * q; pa.cstart4[3] = 6 * q;
    pa.ctotal4 = 10 * q;
    prep_kernel<<<4096 + (10 * q + 255) / 256, 256, 0, stream>>>(pa);

    // 2. LN1 -> z1 (concat bf16)
    lnz_kernel<<<MM, 256, 0, stream>>>(x, ln1_w, ln1_b, z);

    // 3. merged r|k|v|g projection: rkvg = z1 @ W4p^T (silu on g cols)
    gemm8<6><<<dim3(16, 16, 1), 512, 0, stream>>>(z, W4p, rkvg, nullptr, MM, 4096, 2048, 2048);

    // 4. WKV5 chunk-parallel scan (strided over rkvg)
    wkv_p1<<<BB * HH * 4 * PCH, 64, 0, stream>>>(rkvg + 1024, rkvg + 2048, tm_decay, Sloc, 4096);
    wkv_p2<<<BB * HH * 4, 64, 0, stream>>>(tm_decay, Sloc, Sst);
    wkv_p3<<<BB * HH * 4 * PCH, 64, 0, stream>>>(rkvg, rkvg + 1024, rkvg + 2048,
                                                 tm_decay, tm_u, Sst, ybuf, 4096);

    // 5. GroupNorm(y/8) * silu(g) -> og bf16
    gn_kernel<<<MM, 256, 0, stream>>>(ybuf, rkvg + 3072, lnx_w, lnx_b, og);

    // 6. x1 = x + og @ Wo^T  (ring-pipelined 128^2)
    dim3 gr1(CC / 128, MM / 128);
    gemmr<2><<<gr1, 256, 0, stream>>>(og, Wo_b, x1, x, MM, CC, CC);

    // 7. fused LN2 + channel-mix -> xk, xr (bf16)
    ln2m_kernel<<<MM, 256, 0, stream>>>(x1, ln2_w, ln2_b, cm_mix_k, cm_mix_r, xk, xr);

    // 8. kbuf2 = relu(xk @ cm_Wk^T)^2 bf16 ; sr = sigmoid(xr @ cm_Wr^T)
    gemm8<3><<<dim3(16, 16, 1), 512, 0, stream>>>(xk, cmWk_b, nullptr, kbuf2, MM, 4096, 1024, 1024);
    gemmr<4><<<gr1, 256, 0, stream>>>(xr, cmWr_b, sr, nullptr, MM, CC, CC);

    // 9. split-K=4: partials[z] = kbuf2[:, z*1024:(z+1)*1024] @ cm_Wv[:, same]^T
    gemm8<7><<<dim3(4, 16, 4), 512, 0, stream>>>(kbuf2, cmWv_b, partials, nullptr, MM, 1024, 4096, 1024);

    // 10. out = x1 + sr * sum(partials)
    reduce_cmv<<<4096, 256, 0, stream>>>(partials, x1, sr, (float*)d_out);
}